// Round 5
// baseline (223.924 us; speedup 1.0000x reference)
//
#include <hip/hip_runtime.h>
#include <math.h>

#define T_DIM 512
#define TP 8
#define NC 65            // 2*16*2 + 1 candidates
#define NJ 128
#define BLOCK 512        // 8 waves; 2 blocks/CU, all 512 blocks co-resident
#define LOG2E 1.4426950408889634f
#define LN2   0.6931471805599453f
#define CORR_L2 8.617045f   // log2(50257/128)

__device__ __forceinline__ float i2f(int x) { return __int_as_float(x); }
__device__ __forceinline__ int   f2i(float x) { return __float_as_int(x); }

// loss_cos body: serial over j, uniform FP DAG for every candidate (tie-exact)
__device__ __forceinline__ float body_cos(int va, int vs, const int4* pc) {
    float lc0 = 0.f, lc1 = 0.f;
    #pragma unroll 2
    for (int j = 0; j < NJ; j += 2) {
        const int4 a = pc[j * 8];
        const int4 b = pc[(j + 1) * 8];
        {
            const int x = va ^ a.x;
            const float u8 = fmaf((float)__clz(x + 1), 0.0078125f, -0.125f);
            const float d = i2f(f2i(u8) ^ (vs ^ a.y)) + i2f(a.z);
            lc0 = fmaf(d * d, i2f(a.w), lc0);
        }
        {
            const int x = va ^ b.x;
            const float u8 = fmaf((float)__clz(x + 1), 0.0078125f, -0.125f);
            const float d = i2f(f2i(u8) ^ (vs ^ b.y)) + i2f(b.z);
            lc1 = fmaf(d * d, i2f(b.w), lc1);
        }
    }
    return (lc0 + lc1) * 0.0078125f;
}

// loss_cro body: static-M single-exp LSE, uniform FP DAG (tie-exact)
__device__ __forceinline__ float body_cro(int va, int vs, const int4* pc, float M) {
    float z0;
    {
        const int4 a = pc[0];
        const int x = va ^ a.x;
        const float u0 = fmaf((float)__clz(x + 1), 0.0625f, -1.0f);
        const float u = i2f(f2i(u0) ^ (vs ^ a.y));
        z0 = fmaf(u, i2f(a.w), i2f(a.z)) - M;
    }
    float s0 = __builtin_amdgcn_exp2f(z0), s1;
    {
        const int4 a = pc[8];
        const int x = va ^ a.x;
        const float u0 = fmaf((float)__clz(x + 1), 0.0625f, -1.0f);
        const float u = i2f(f2i(u0) ^ (vs ^ a.y));
        s1 = __builtin_amdgcn_exp2f(fmaf(u, i2f(a.w), i2f(a.z)) - M);
    }
    #pragma unroll 2
    for (int k = 2; k < NJ; k += 2) {
        const int4 a = pc[k * 8];
        const int4 b = pc[(k + 1) * 8];
        {
            const int x = va ^ a.x;
            const float u0 = fmaf((float)__clz(x + 1), 0.0625f, -1.0f);
            const float u = i2f(f2i(u0) ^ (vs ^ a.y));
            s0 += __builtin_amdgcn_exp2f(fmaf(u, i2f(a.w), i2f(a.z)) - M);
        }
        {
            const int x = va ^ b.x;
            const float u0 = fmaf((float)__clz(x + 1), 0.0625f, -1.0f);
            const float u = i2f(f2i(u0) ^ (vs ^ b.y));
            s1 += __builtin_amdgcn_exp2f(fmaf(u, i2f(b.w), i2f(b.z)) - M);
        }
    }
    const float S = fmaxf(s0 + s1, 1e-38f);
    return (__builtin_amdgcn_logf(S) - z0) * LN2;
}

__device__ __forceinline__ int cand_v(int c, int sta, const int* s_rand, int p) {
    if (c == 32) return sta;
    const int cc = (c < 32) ? c : (c - 33);
    const int h = cc >> 1;
    const int r = (sta ^ (1 << h)) ^ (s_rand[cc * TP + p] & ((1 << h) - 1));
    return (c < 32) ? r : -r;
}

// ---------------- fused kernel: grid 512, block 512 ----------------
__global__ __launch_bounds__(BLOCK, 4) void cg_fused(
    const int* __restrict__ sta_loc,    // (T, 8)
    const int* __restrict__ nei_loc,    // (T, 128, 8)
    const int* __restrict__ voc_loc,    // (T, 128, 8)
    const float* __restrict__ sta_emb,  // (T, 256)
    const float* __restrict__ nei_emb,  // (T, 128, 256)
    const float* __restrict__ voc_emb,  // (T, 128, 256)
    const int* __restrict__ rand_masks, // (T, 32, 8)
    float* __restrict__ out)
{
    const int t = blockIdx.x;
    const int tid = threadIdx.x;

    __shared__ int4  s_pc4[2][NJ * TP];   // 32 KB: {qa, qsgn, B|C, ae|A}
    __shared__ float s_cspT[2][TP * 132]; // transposed csp, padded (8.4 KB)
    __shared__ float s_css[2][NJ];
    __shared__ float s_w[2][NJ];          // eu (side0) or A_k (side1)
    __shared__ float s_dot[NJ];           // nei only
    __shared__ float s_nn[2][NJ];
    __shared__ float s_lcos[NC * TP], s_lcro[NC * TP];
    __shared__ float s_Mpart[8 * 8];
    __shared__ float s_ss;
    __shared__ int   s_sta[TP];
    __shared__ int   s_rand[256];

    if (tid < TP) s_sta[tid] = sta_loc[t * TP + tid];
    if (tid < 256) s_rand[tid] = rand_masks[t * 256 + tid];

    // ---- P1: embedding partial sums. idx = tid>>1 (0..255), interleaved sides
    //      side_r = idx&1, row = idx>>1; sub = tid&1 covers 128 elems each ----
    {
        const int idx = tid >> 1, sub = tid & 1;
        const int side_r = idx & 1, row = idx >> 1;
        const float* emb = side_r ? voc_emb : nei_emb;
        const float4* ep = (const float4*)(emb + ((size_t)t * NJ + row) * 256) + sub * 32;
        const float4* sp = (const float4*)(sta_emb + (size_t)t * 256) + sub * 32;
        float dd = 0.f, nn = 0.f, ss = 0.f;
        #pragma unroll 4
        for (int i = 0; i < 32; ++i) {
            const float4 b = ep[i];
            nn += b.x * b.x + b.y * b.y + b.z * b.z + b.w * b.w;
            if (side_r == 0) {
                const float4 a = sp[i];
                dd += a.x * b.x + a.y * b.y + a.z * b.z + a.w * b.w;
                if (row == 0) ss += a.x * a.x + a.y * a.y + a.z * a.z + a.w * a.w;
            }
        }
        nn += __shfl_xor(nn, 1);
        if (side_r == 0) { dd += __shfl_xor(dd, 1); ss += __shfl_xor(ss, 1); }
        if (sub == 0) {
            s_nn[side_r][row] = nn;
            if (side_r == 0) { s_dot[row] = dd; if (row == 0) s_ss = ss; }
        }
    }

    // ---- P2: stage qa/qsgn + csp (transposed). 2048 items, 4 per thread ----
    {
        #pragma unroll
        for (int k = 0; k < 4; ++k) {
            const int item = tid + k * 512;
            const int side = item >> 10, idx = item & 1023;
            const int* loc = side ? voc_loc : nei_loc;
            const int pl = loc[t * (NJ * TP) + idx];
            const int qa = pl < 0 ? -pl : pl;
            const int qsgn = pl & 0x80000000;
            const int sta = s_sta[idx & 7];
            const int sa = sta < 0 ? -sta : sta;
            const int x = sa ^ qa;
            const float u0 = fmaf((float)__clz(x + 1), 0.0625f, -1.0f);
            const float csp = i2f(f2i(u0) ^ ((sta ^ pl) & 0x80000000));
            ((int2*)&s_pc4[side][idx])[0] = make_int2(qa, qsgn);
            s_cspT[side][(idx & 7) * 132 + (idx >> 3)] = csp;
        }
    }
    __syncthreads();

    // ---- P3: css reduce + eu / A. 256 threads: j = tid>>1, side = tid&1 ----
    if (tid < 256) {
        const int j = tid >> 1, side = tid & 1;
        float cs = 0.f;
        #pragma unroll
        for (int p = 0; p < TP; ++p) cs += s_cspT[side][p * 132 + j];
        s_css[side][j] = cs;
        const float ns = sqrtf(s_ss);
        const float nn = s_nn[side][j];
        if (side == 0)
            s_w[0][j] = s_dot[j] / (fmaxf(sqrtf(nn), 1e-12f) * fmaxf(ns, 1e-12f));
        else
            s_w[1][j] = ns * sqrtf(nn) * (0.125f * LOG2E);   // A_k (>= 0)
    }
    __syncthreads();

    // ---- P4: repack {B|C, ae|A}; per-(wave,p) max of (C + A) for side1 ----
    {
        float mloc = -INFINITY;
        #pragma unroll
        for (int k = 0; k < 4; ++k) {
            const int item = tid + k * 512;
            const int side = item >> 10, idx = item & 1023;
            const int j = idx >> 3, p = idx & 7;
            const float csp = s_cspT[side][p * 132 + j];
            const float b = s_css[side][j] - csp;
            const float w = s_w[side][j];
            float z2, w2;
            if (side == 0) { z2 = fmaf(b, 0.125f, -w); w2 = fabsf(w); }
            else {
                z2 = fmaf(b, w, j ? CORR_L2 : 0.0f);
                w2 = w;
                mloc = fmaxf(mloc, z2 + w);
            }
            ((int2*)&s_pc4[side][idx])[1] = make_int2(f2i(z2), f2i(w2));
        }
        mloc = fmaxf(mloc, __shfl_xor(mloc, 8));
        mloc = fmaxf(mloc, __shfl_xor(mloc, 16));
        mloc = fmaxf(mloc, __shfl_xor(mloc, 32));
        const int lane = tid & 63;
        if (lane < 8) s_Mpart[(tid >> 6) * 8 + lane] = mloc;
    }
    __syncthreads();

    // ---- P5: 1040 units (520 cos + 520 cro) in 3 strided passes ----
    {
        #pragma unroll
        for (int pass = 0; pass < 3; ++pass) {
            const int u = tid + pass * 512;
            if (u < 2 * NC * TP) {
                const int side = (u >= NC * TP);
                const int w = u - side * (NC * TP);
                const int c = w >> 3, p = w & 7;
                const int v = cand_v(c, s_sta[p], s_rand, p);
                const int va = v < 0 ? -v : v;
                const int vs = v & 0x80000000;
                if (side == 0) {
                    s_lcos[w] = body_cos(va, vs, s_pc4[0] + p);
                } else {
                    float M = s_Mpart[p];
                    #pragma unroll
                    for (int wv = 1; wv < 8; ++wv) M = fmaxf(M, s_Mpart[wv * 8 + p]);
                    s_lcro[w] = body_cro(va, vs, s_pc4[1] + p, M);
                }
            }
        }
    }
    __syncthreads();

    // ---- P6: argmin (first-min) + gather + means, in-block ----
    float vc = 0.f, vr = 0.f, vt = 0.f;
    if (tid < TP) {
        const int p = tid;
        float best = INFINITY, blc = 0.f, blr = 0.f;
        int bc = 0;
        for (int c = 0; c < NC; ++c) {
            const float lc = s_lcos[c * TP + p];
            const float lr = s_lcro[c * TP + p];
            const float lt = fmaf(0.1f, lr, lc);
            if (lt < best) { best = lt; bc = c; blc = lc; blr = lr; }
        }
        out[t * TP + p] = (float)cand_v(bc, s_sta[p], s_rand, p);
        vc = blc; vr = blr; vt = best;
    }
    if (tid < 64) {
        vc += __shfl_xor(vc, 1); vc += __shfl_xor(vc, 2); vc += __shfl_xor(vc, 4);
        vr += __shfl_xor(vr, 1); vr += __shfl_xor(vr, 2); vr += __shfl_xor(vr, 4);
        vt += __shfl_xor(vt, 1); vt += __shfl_xor(vt, 2); vt += __shfl_xor(vt, 4);
        if (tid == 0) {
            out[T_DIM * TP + t] = vc * 0.125f;
            out[T_DIM * TP + T_DIM + t] = vr * 0.125f;
            out[T_DIM * TP + 2 * T_DIM + t] = vt * 0.125f;
        }
    }
}

extern "C" void kernel_launch(void* const* d_in, const int* in_sizes, int n_in,
                              void* d_out, int out_size, void* d_ws, size_t ws_size,
                              hipStream_t stream) {
    const int* sta_loc = (const int*)d_in[0];
    const int* nei_loc = (const int*)d_in[1];
    const int* voc_loc = (const int*)d_in[2];
    const float* sta_emb = (const float*)d_in[3];
    const float* nei_emb = (const float*)d_in[4];
    const float* voc_emb = (const float*)d_in[5];
    const int* rand_masks = (const int*)d_in[6];
    float* out = (float*)d_out;

    cg_fused<<<T_DIM, BLOCK, 0, stream>>>(
        sta_loc, nei_loc, voc_loc, sta_emb, nei_emb, voc_emb, rand_masks, out);
}

// Round 6
// 197.886 us; speedup vs baseline: 1.1316x; 1.1316x over previous
//
#include <hip/hip_runtime.h>
#include <math.h>

#define T_DIM 512
#define TP 8
#define NC 65            // 2*16*2 + 1 candidates
#define NJ 128
#define BLOCK 576        // 9 waves: 0-7 compute, 8 stages/leftovers
#define LOG2E 1.4426950408889634f
#define LN2   0.6931471805599453f
#define CORR_L2 8.617045f   // log2(50257/128)

__device__ __forceinline__ float i2f(int x) { return __int_as_float(x); }
__device__ __forceinline__ int   f2i(float x) { return __float_as_int(x); }

__device__ __forceinline__ int cand_v(int c, int sta, const int* s_rand, int p) {
    if (c == 32) return sta;
    const int cc = (c < 32) ? c : (c - 33);
    const int h = cc >> 1;
    const int r = (sta ^ (1 << h)) ^ (s_rand[cc * TP + p] & ((1 << h) - 1));
    return (c < 32) ? r : -r;
}

// one cos term: d = csim/8 + B; acc += d*d*|eu|   (uniform DAG per candidate)
#define COS_STEP(va, vs, X, acc) do {                                   \
    const int _x = (va) ^ (X).x;                                        \
    const float _u8 = fmaf((float)__clz(_x + 1), 0.0078125f, -0.125f);  \
    const float _d = i2f(f2i(_u8) ^ ((vs) ^ (X).y)) + i2f((X).z);       \
    (acc) = fmaf(_d * _d, i2f((X).w), (acc));                           \
} while (0)

// one cro z-term (log2 domain): z = u*A + C
#define CRO_Z(va, vs, X) ({                                             \
    const int _x = (va) ^ (X).x;                                        \
    const float _u0 = fmaf((float)__clz(_x + 1), 0.0625f, -1.0f);       \
    const float _u = i2f(f2i(_u0) ^ ((vs) ^ (X).y));                    \
    fmaf(_u, i2f((X).w), i2f((X).z));                                   \
})

__device__ __forceinline__ float cos_body1(int va, int vs, const int4* pc) {
    float a0 = 0.f, a1 = 0.f;
    #pragma unroll 2
    for (int j = 0; j < NJ; j += 2) {
        const int4 x = pc[j * 8];
        const int4 y = pc[(j + 1) * 8];
        COS_STEP(va, vs, x, a0);
        COS_STEP(va, vs, y, a1);
    }
    return (a0 + a1) * 0.0078125f;
}

__device__ __forceinline__ void cos_body2(int vaA, int vsA, int vaB, int vsB,
                                          const int4* pc, float* oA, float* oB) {
    float a0 = 0.f, a1 = 0.f, b0 = 0.f, b1 = 0.f;
    #pragma unroll 2
    for (int j = 0; j < NJ; j += 2) {
        const int4 x = pc[j * 8];
        const int4 y = pc[(j + 1) * 8];
        COS_STEP(vaA, vsA, x, a0);
        COS_STEP(vaB, vsB, x, b0);
        COS_STEP(vaA, vsA, y, a1);
        COS_STEP(vaB, vsB, y, b1);
    }
    *oA = (a0 + a1) * 0.0078125f;
    *oB = (b0 + b1) * 0.0078125f;
}

__device__ __forceinline__ float cro_body1(int va, int vs, const int4* pc, float M) {
    const int4 x0 = pc[0];
    const float z0 = CRO_Z(va, vs, x0) - M;
    float s0 = __builtin_amdgcn_exp2f(z0);
    const int4 x1 = pc[8];
    float s1 = __builtin_amdgcn_exp2f(CRO_Z(va, vs, x1) - M);
    #pragma unroll 2
    for (int k = 2; k < NJ; k += 2) {
        const int4 x = pc[k * 8];
        const int4 y = pc[(k + 1) * 8];
        s0 += __builtin_amdgcn_exp2f(CRO_Z(va, vs, x) - M);
        s1 += __builtin_amdgcn_exp2f(CRO_Z(va, vs, y) - M);
    }
    const float S = fmaxf(s0 + s1, 1e-38f);
    return (__builtin_amdgcn_logf(S) - z0) * LN2;
}

__device__ __forceinline__ void cro_body2(int vaA, int vsA, int vaB, int vsB,
                                          const int4* pc, float M, float* oA, float* oB) {
    const int4 x0 = pc[0];
    const float zA0 = CRO_Z(vaA, vsA, x0) - M;
    const float zB0 = CRO_Z(vaB, vsB, x0) - M;
    float sA0 = __builtin_amdgcn_exp2f(zA0);
    float sB0 = __builtin_amdgcn_exp2f(zB0);
    const int4 x1 = pc[8];
    float sA1 = __builtin_amdgcn_exp2f(CRO_Z(vaA, vsA, x1) - M);
    float sB1 = __builtin_amdgcn_exp2f(CRO_Z(vaB, vsB, x1) - M);
    #pragma unroll 2
    for (int k = 2; k < NJ; k += 2) {
        const int4 x = pc[k * 8];
        const int4 y = pc[(k + 1) * 8];
        sA0 += __builtin_amdgcn_exp2f(CRO_Z(vaA, vsA, x) - M);
        sB0 += __builtin_amdgcn_exp2f(CRO_Z(vaB, vsB, x) - M);
        sA1 += __builtin_amdgcn_exp2f(CRO_Z(vaA, vsA, y) - M);
        sB1 += __builtin_amdgcn_exp2f(CRO_Z(vaB, vsB, y) - M);
    }
    const float SA = fmaxf(sA0 + sA1, 1e-38f);
    const float SB = fmaxf(sB0 + sB1, 1e-38f);
    *oA = (__builtin_amdgcn_logf(SA) - zA0) * LN2;
    *oB = (__builtin_amdgcn_logf(SB) - zB0) * LN2;
}

// ---------------- fused kernel: grid 512, block 576 ----------------
__global__ __launch_bounds__(BLOCK, 5) void cg_fused(
    const int* __restrict__ sta_loc,    // (T, 8)
    const int* __restrict__ nei_loc,    // (T, 128, 8)
    const int* __restrict__ voc_loc,    // (T, 128, 8)
    const float* __restrict__ sta_emb,  // (T, 256)
    const float* __restrict__ nei_emb,  // (T, 128, 256)
    const float* __restrict__ voc_emb,  // (T, 128, 256)
    const int* __restrict__ rand_masks, // (T, 32, 8)
    float* __restrict__ out)
{
    const int t = blockIdx.x;
    const int tid = threadIdx.x;

    __shared__ int4  s_pc4[2][NJ * TP];   // 32 KB: {qa, qsgn, B|C, ae|A}
    __shared__ float s_cspT[2][TP * 132]; // transposed csp, padded
    __shared__ float s_css[2][NJ];
    __shared__ float s_w[2][NJ];          // eu (side0) or A_k (side1)
    __shared__ float s_dot[NJ];           // nei only
    __shared__ float s_nn[2][NJ];
    __shared__ float s_lcos[NC * TP], s_lcro[NC * TP];
    __shared__ float s_Mpart[9 * 8];
    __shared__ float s_ss;
    __shared__ int   s_sta[TP];
    __shared__ int   s_rand[256];

    if (tid < 256) s_rand[tid] = rand_masks[t * 256 + tid];

    if (tid < 512) {
        // ---- P1 (waves 0-7): embedding sums, 4 lanes/row, 64B-line groups ----
        const int g = tid >> 2, sub = tid & 3;
        const float4* sp = (const float4*)(sta_emb + (size_t)t * 256);
        const float4* np = (const float4*)(nei_emb + ((size_t)t * NJ + g) * 256);
        const float4* vp = (const float4*)(voc_emb + ((size_t)t * NJ + g) * 256);
        float dd = 0.f, nnn = 0.f, nnv = 0.f, ss = 0.f;
        #pragma unroll 4
        for (int i = 0; i < 16; ++i) {
            const int i4 = sub + 4 * i;            // lanes 0-3 span one 64B line
            const float4 a = sp[i4];
            const float4 b = np[i4];
            const float4 c = vp[i4];
            dd  += a.x * b.x + a.y * b.y + a.z * b.z + a.w * b.w;
            nnn += b.x * b.x + b.y * b.y + b.z * b.z + b.w * b.w;
            nnv += c.x * c.x + c.y * c.y + c.z * c.z + c.w * c.w;
            if (g == 0) ss += a.x * a.x + a.y * a.y + a.z * a.z + a.w * a.w;
        }
        dd  += __shfl_xor(dd, 1);  dd  += __shfl_xor(dd, 2);
        nnn += __shfl_xor(nnn, 1); nnn += __shfl_xor(nnn, 2);
        nnv += __shfl_xor(nnv, 1); nnv += __shfl_xor(nnv, 2);
        if (g == 0) { ss += __shfl_xor(ss, 1); ss += __shfl_xor(ss, 2); }
        if (sub == 0) {
            s_dot[g] = dd; s_nn[0][g] = nnn; s_nn[1][g] = nnv;
            if (g == 0) s_ss = ss;
        }
    } else {
        // ---- P2 (wave 8, overlapped with P1): stage loc -> qa/qsgn + cspT ----
        const int l = tid - 512;                    // 0..63
        if (l < TP) s_sta[l] = sta_loc[t * TP + l];
        const int4 sta4 = ((const int4*)(sta_loc + t * TP))[l & 1];
        const int sarr[4] = {sta4.x, sta4.y, sta4.z, sta4.w};
        #pragma unroll
        for (int side = 0; side < 2; ++side) {
            const int* loc = side ? voc_loc : nei_loc;
            const int4* lp = (const int4*)(loc + (size_t)t * 1024);
            #pragma unroll
            for (int q = 0; q < 4; ++q) {
                const int4 pl4 = lp[q * 64 + l];
                const int j = q * 32 + (l >> 1);
                const int parr[4] = {pl4.x, pl4.y, pl4.z, pl4.w};
                #pragma unroll
                for (int e = 0; e < 4; ++e) {
                    const int pl = parr[e];
                    const int sta = sarr[e];
                    const int idx = q * 256 + 4 * l + e;
                    const int qa = pl < 0 ? -pl : pl;
                    const int qsgn = pl & 0x80000000;
                    const int sa = sta < 0 ? -sta : sta;
                    const int x = sa ^ qa;
                    const float u0 = fmaf((float)__clz(x + 1), 0.0625f, -1.0f);
                    const float csp = i2f(f2i(u0) ^ ((sta ^ pl) & 0x80000000));
                    ((int2*)&s_pc4[side][idx])[0] = make_int2(qa, qsgn);
                    s_cspT[side][(4 * (l & 1) + e) * 132 + j] = csp;
                }
            }
        }
    }
    __syncthreads();

    // ---- P3: css reduce + eu / A. 256 threads: j = tid>>1, side = tid&1 ----
    if (tid < 256) {
        const int j = tid >> 1, side = tid & 1;
        float cs = 0.f;
        #pragma unroll
        for (int p = 0; p < TP; ++p) cs += s_cspT[side][p * 132 + j];
        s_css[side][j] = cs;
        const float ns = sqrtf(s_ss);
        const float nn = s_nn[side][j];
        if (side == 0)
            s_w[0][j] = s_dot[j] / (fmaxf(sqrtf(nn), 1e-12f) * fmaxf(ns, 1e-12f));
        else
            s_w[1][j] = ns * sqrtf(nn) * (0.125f * LOG2E);   // A_k (>= 0)
    }
    __syncthreads();

    // ---- P4: repack {B|C, ae|A}; per-(wave,p) max of (C + A) for side1 ----
    {
        float mloc = -INFINITY;
        #pragma unroll
        for (int k = 0; k < 4; ++k) {
            const int item = tid + k * BLOCK;       // BLOCK%8==0: p invariant
            if (item < 2048) {
                const int side = item >> 10, idx = item & 1023;
                const int j = idx >> 3, p = idx & 7;
                const float csp = s_cspT[side][p * 132 + j];
                const float b = s_css[side][j] - csp;
                const float w = s_w[side][j];
                float z2, w2;
                if (side == 0) { z2 = fmaf(b, 0.125f, -w); w2 = fabsf(w); }
                else {
                    z2 = fmaf(b, w, j ? CORR_L2 : 0.0f);
                    w2 = w;
                    mloc = fmaxf(mloc, z2 + w);
                }
                ((int2*)&s_pc4[side][idx])[1] = make_int2(f2i(z2), f2i(w2));
            }
        }
        mloc = fmaxf(mloc, __shfl_xor(mloc, 8));
        mloc = fmaxf(mloc, __shfl_xor(mloc, 16));
        mloc = fmaxf(mloc, __shfl_xor(mloc, 32));
        const int lane = tid & 63;
        if (lane < 8) s_Mpart[(tid >> 6) * 8 + lane] = mloc;
    }
    __syncthreads();

    // ---- P5: 2 candidates per thread sharing one LDS stream ----
    if (tid < 256) {                    // waves 0-3: cos, c = {2gk, 2gk+1}
        const int gk = tid >> 3, p = tid & 7;
        const int sta = s_sta[p];
        const int vA = cand_v(2 * gk, sta, s_rand, p);
        const int vB = cand_v(2 * gk + 1, sta, s_rand, p);
        cos_body2(vA < 0 ? -vA : vA, vA & 0x80000000,
                  vB < 0 ? -vB : vB, vB & 0x80000000, s_pc4[0] + p,
                  &s_lcos[(2 * gk) * TP + p], &s_lcos[(2 * gk + 1) * TP + p]);
    } else if (tid < 512) {             // waves 4-7: cro
        const int w = tid - 256, gk = w >> 3, p = w & 7;
        const int sta = s_sta[p];
        const int vA = cand_v(2 * gk, sta, s_rand, p);
        const int vB = cand_v(2 * gk + 1, sta, s_rand, p);
        float M = s_Mpart[p];
        #pragma unroll
        for (int wv = 1; wv < 9; ++wv) M = fmaxf(M, s_Mpart[wv * 8 + p]);
        cro_body2(vA < 0 ? -vA : vA, vA & 0x80000000,
                  vB < 0 ? -vB : vB, vB & 0x80000000, s_pc4[1] + p, M,
                  &s_lcro[(2 * gk) * TP + p], &s_lcro[(2 * gk + 1) * TP + p]);
    } else if (tid < 520) {             // wave 8: c=64 cos
        const int p = tid - 512;
        const int v = cand_v(64, s_sta[p], s_rand, p);
        s_lcos[64 * TP + p] =
            cos_body1(v < 0 ? -v : v, v & 0x80000000, s_pc4[0] + p);
    } else if (tid < 528) {             // wave 8: c=64 cro
        const int p = tid - 520;
        const int v = cand_v(64, s_sta[p], s_rand, p);
        float M = s_Mpart[p];
        #pragma unroll
        for (int wv = 1; wv < 9; ++wv) M = fmaxf(M, s_Mpart[wv * 8 + p]);
        s_lcro[64 * TP + p] =
            cro_body1(v < 0 ? -v : v, v & 0x80000000, s_pc4[1] + p, M);
    }
    __syncthreads();

    // ---- P6: argmin (first-min) + gather + means, in-block ----
    float vc = 0.f, vr = 0.f, vt = 0.f;
    if (tid < TP) {
        const int p = tid;
        float best = INFINITY, blc = 0.f, blr = 0.f;
        int bc = 0;
        for (int c = 0; c < NC; ++c) {
            const float lc = s_lcos[c * TP + p];
            const float lr = s_lcro[c * TP + p];
            const float lt = fmaf(0.1f, lr, lc);
            if (lt < best) { best = lt; bc = c; blc = lc; blr = lr; }
        }
        out[t * TP + p] = (float)cand_v(bc, s_sta[p], s_rand, p);
        vc = blc; vr = blr; vt = best;
    }
    if (tid < 64) {
        vc += __shfl_xor(vc, 1); vc += __shfl_xor(vc, 2); vc += __shfl_xor(vc, 4);
        vr += __shfl_xor(vr, 1); vr += __shfl_xor(vr, 2); vr += __shfl_xor(vr, 4);
        vt += __shfl_xor(vt, 1); vt += __shfl_xor(vt, 2); vt += __shfl_xor(vt, 4);
        if (tid == 0) {
            out[T_DIM * TP + t] = vc * 0.125f;
            out[T_DIM * TP + T_DIM + t] = vr * 0.125f;
            out[T_DIM * TP + 2 * T_DIM + t] = vt * 0.125f;
        }
    }
}

extern "C" void kernel_launch(void* const* d_in, const int* in_sizes, int n_in,
                              void* d_out, int out_size, void* d_ws, size_t ws_size,
                              hipStream_t stream) {
    const int* sta_loc = (const int*)d_in[0];
    const int* nei_loc = (const int*)d_in[1];
    const int* voc_loc = (const int*)d_in[2];
    const float* sta_emb = (const float*)d_in[3];
    const float* nei_emb = (const float*)d_in[4];
    const float* voc_emb = (const float*)d_in[5];
    const int* rand_masks = (const int*)d_in[6];
    float* out = (float*)d_out;

    cg_fused<<<T_DIM, BLOCK, 0, stream>>>(
        sta_loc, nei_loc, voc_loc, sta_emb, nei_emb, voc_emb, rand_masks, out);
}